// Round 4
// baseline (411.739 us; speedup 1.0000x reference)
//
#include <hip/hip_runtime.h>

#define GN 4096
#define GF 128
#define GB 4

typedef __attribute__((ext_vector_type(8))) short short8;
typedef __attribute__((ext_vector_type(4))) float floatx4;
typedef __attribute__((ext_vector_type(4))) int intx4;

static __device__ __forceinline__ unsigned short f2bf(float x){
  unsigned int u = __float_as_uint(x);
  u += 0x7FFFu + ((u >> 16) & 1u);            // RNE
  return (unsigned short)(u >> 16);
}

// J4-permutation (4-way parity within each 256-j window) so gat_main reads adj as dwordx4:
// lane l component k <-> j = 4l + k; table index J = (j&~255) + 64*(j&3) + ((j&255)>>2).
// whB / E / F are all written in J-order; bits, fragments, tables then agree untouched.

// ---------- Kernel 1: Wh = h@W (f32), si, bf16 E/F tables, bf16 Wh fragment-major ----------
__global__ __launch_bounds__(256)
void gat_prep(const float* __restrict__ h, const float* __restrict__ W,
              const float* __restrict__ a, unsigned short* __restrict__ whB,
              float* __restrict__ si_g, unsigned short* __restrict__ EFh)
{
  __shared__ float hl[16*GF];                  // 8 KB
  __shared__ float red[2][2][16];
  const int tid = threadIdx.x;
  const int b   = blockIdx.x >> 8;
  const int r0  = (blockIdx.x & 255) << 4;
  const int o = tid & 127, g = tid >> 7;

  const float4* hb4 = (const float4*)(h + ((size_t)(b*GN + r0))*GF);
  ((float4*)hl)[tid]       = hb4[tid];
  ((float4*)hl)[tid + 256] = hb4[tid + 256];
  __syncthreads();

  float acc[8];
  #pragma unroll
  for (int r=0;r<8;++r) acc[r] = 0.f;
  const float* Wp = W + o;
  for (int f4=0; f4<32; ++f4){
    const float w0 = Wp[(f4*4+0)*GF];
    const float w1 = Wp[(f4*4+1)*GF];
    const float w2 = Wp[(f4*4+2)*GF];
    const float w3 = Wp[(f4*4+3)*GF];
    #pragma unroll
    for (int r=0;r<8;++r){
      const float4 h4 = *(const float4*)&hl[((g<<3)+r)*GF + (f4<<2)];
      acc[r] = fmaf(h4.x, w0, acc[r]);
      acc[r] = fmaf(h4.y, w1, acc[r]);
      acc[r] = fmaf(h4.z, w2, acc[r]);
      acc[r] = fmaf(h4.w, w3, acc[r]);
    }
  }

  const float ai = a[o], aj = a[GF + o];
  const int lane = tid & 63, wh = (tid >> 6) & 1;
  #pragma unroll
  for (int r=0;r<8;++r){
    float vi = acc[r]*ai, vj = acc[r]*aj;
    #pragma unroll
    for (int off=32; off; off>>=1){ vi += __shfl_down(vi, off); vj += __shfl_down(vj, off); }
    if (lane == 0){ red[0][wh][(g<<3)+r] = vi; red[1][wh][(g<<3)+r] = vj; }
  }

  // fragment-major bf16 store in J4-order: r=c and r=c+4 -> J = Jb+64c, Jb+64c+1
  unsigned short us[8] __attribute__((aligned(16)));
  #pragma unroll
  for (int r=0;r<8;++r) us[r] = f2bf(acc[r]);
  {
    const int j0 = r0 + (g<<3);
    const int Jb = (j0 & ~255) + ((j0 & 255) >> 2);
    unsigned short* d0 = whB + (((size_t)(b*128 + (Jb>>5))*128 + o)<<5) + (Jb&31);
    #pragma unroll
    for (int c=0;c<4;++c){
      const unsigned int w = (unsigned int)us[c] | ((unsigned int)us[c+4] << 16);
      *(unsigned int*)(d0 + 8192*c) = w;       // +64 J -> +2 jblks = +8192 shorts
    }
  }

  __syncthreads();
  if (tid < 16){
    si_g[b*GN + r0 + tid] = red[0][0][tid] + red[0][1][tid];
  } else if (tid < 32){
    const int r = tid - 16;
    const int jj = r0 + r;
    const int J  = (jj & ~255) + ((jj & 3) << 6) + ((jj & 255) >> 2);
    const float vsj = red[1][0][r] + red[1][1][r];
    EFh[(size_t)b*8192 + J]        = f2bf(__expf(vsj));
    EFh[(size_t)b*8192 + 4096 + J] = f2bf(__expf(0.2f*vsj));
  }
}

// ---------- Kernel 2: fused adj-stream + attention + PV ----------
// adj read as dwordx4 (1KB contiguous per row-visit) over 256-j superchunks,
// prefetched in two 16-row half-batches; FIFO discipline: Bc always oldest at
// each COMPUTE, vv half-batch drains exactly one COMPUTE later, ballots stall-free.
__global__ __launch_bounds__(256, 2)
void gat_main(const int* __restrict__ adj, const unsigned short* __restrict__ whB,
              const float* __restrict__ si_g, const unsigned short* __restrict__ EFh,
              float* __restrict__ out)
{
  __shared__ __align__(16) char smem[34304];
  unsigned short* sEj = (unsigned short*)smem;                       // [0,4096):E [4096,8192):F (bf16, J-order)
  unsigned long long* bits64 = (unsigned long long*)(smem + 16384);  // [4 waves][2 buf][32 rows][4 k] = 8 KB
  float* smemc = (float*)smem;                                       // combine (after K-loop)

  const int tid  = threadIdx.x;
  const int wave = tid >> 6, lane = tid & 63;
  const int b  = (blockIdx.x >> 1) & 3;                              // XCD-pair per batch
  const int i0 = ((((blockIdx.x >> 3) << 1) | (blockIdx.x & 1))) << 5;
  const int m = lane & 15, quad = lane >> 4, q8 = quad << 3;
  const int jw = wave << 10, jw32 = wave << 5;
  const int rrot = wave << 3;

  const intx4* adjb4 = (const intx4*)(adj + ((size_t)(b*GN + i0))*GN + jw) + lane;

#define LOADVV(vv_, sc_, h_) do { \
    _Pragma("unroll") \
    for (int r=0;r<16;++r){ \
      const int rr = (r + rrot + ((h_)<<4)) & 31; \
      vv_[r] = __builtin_nontemporal_load(adjb4 + ((sc_)<<6) + rr*(GN/4)); \
    } \
  } while(0)

  // prologue: both half-batches of superchunk 0 in flight before anything else
  intx4 vv[16];
  LOADVV(vv, 0, 0);
  intx4 vp[16];
  LOADVV(vp, 0, 1);

  const float si0 = si_g[(size_t)b*GN + i0 + m];
  const float si1 = si_g[(size_t)b*GN + i0 + 16 + m];
  const float Ri0 = __expf(-0.8f*si0), Ri1 = __expf(-0.8f*si1);
  const unsigned short* lanebase = whB + ((size_t)b<<19) + (m<<5) + q8;

  // --- EF staging (16KB, already J-ordered) ---
  {
    const uint4* Eg = (const uint4*)(EFh + (size_t)b*8192);
    uint4* sE4 = (uint4*)sEj;
    #pragma unroll
    for (int k=0;k<4;++k) sE4[tid + (k<<8)] = Eg[tid + (k<<8)];
  }

  floatx4 acc0[8], acc1[8];
  #pragma unroll
  for (int c=0;c<8;++c){ acc0[c] = (floatx4){0.f,0.f,0.f,0.f}; acc1[c] = (floatx4){0.f,0.f,0.f,0.f}; }
  floatx4 lf0 = (floatx4){0.f,0.f,0.f,0.f}, lf1 = (floatx4){0.f,0.f,0.f,0.f};
  const short8 ones8 = {0x3F80,0x3F80,0x3F80,0x3F80,0x3F80,0x3F80,0x3F80,0x3F80};

// ballot-pack one 16-row half-batch: 4 masks per row (components k=0..3)
#define BALLOTS(vv_, scdst_, h_) do { \
    unsigned long long* bw = bits64 + (((wave<<1) | ((scdst_)&1)) << 7); \
    _Pragma("unroll") \
    for (int r=0;r<16;++r){ \
      const int rr = (r + rrot + ((h_)<<4)) & 31; \
      const unsigned long long m0 = __ballot(vv_[r].x > 0); \
      const unsigned long long m1 = __ballot(vv_[r].y > 0); \
      const unsigned long long m2 = __ballot(vv_[r].z > 0); \
      const unsigned long long m3 = __ballot(vv_[r].w > 0); \
      if (lane == 0){ \
        bw[(rr<<2)]   = m0; bw[(rr<<2)|1] = m1; \
        bw[(rr<<2)|2] = m2; bw[(rr<<2)|3] = m3; \
      } \
    } \
    asm volatile("s_waitcnt lgkmcnt(0)" ::: "memory"); \
  } while(0)

#define BCLOAD(Bc_, ch_) do { \
    const unsigned short* wb = lanebase + ((size_t)(jw32 + ((ch_)<<1)) << 12); \
    _Pragma("unroll") \
    for (int c=0;c<8;++c) Bc_[c]   = *(const short8*)(wb + (c<<9)); \
    _Pragma("unroll") \
    for (int c=0;c<8;++c) Bc_[8+c] = *(const short8*)(wb + 4096 + (c<<9)); \
  } while(0)

// one 64-J chunk (= parity class k of superchunk sc): 2 t-steps of 32 J
#define COMPUTE_CH(sc_, k_, Bc_) do { \
    const unsigned int* bwp = (const unsigned int*)(bits64 + (((wave<<1) | ((sc_)&1)) << 7)); \
    _Pragma("unroll") \
    for (int t=0;t<2;++t){ \
      const unsigned int sh0 = bwp[(m<<3)|((k_)<<1)|t] >> q8; \
      const unsigned int sh1 = bwp[((m+16)<<3)|((k_)<<1)|t] >> q8; \
      const int jj = jw + ((sc_)<<8) + ((k_)<<6) + (t<<5) + q8; \
      const short8 Es = *(const short8*)&sEj[jj]; \
      const short8 Fs = *(const short8*)&sEj[4096 + jj]; \
      const unsigned int* Eu = (const unsigned int*)&Es; \
      const unsigned int* Fu = (const unsigned int*)&Fs; \
      unsigned int aw0[4], aw1[4]; \
      _Pragma("unroll") \
      for (int p=0;p<4;++p){ \
        const float E0 = __uint_as_float(Eu[p] << 16); \
        const float E1 = __uint_as_float(Eu[p] & 0xFFFF0000u); \
        const float F0 = __uint_as_float(Fu[p] << 16); \
        const float F1 = __uint_as_float(Fu[p] & 0xFFFF0000u); \
        const float p00 = fmaxf(E0, Ri0*F0), p01 = fmaxf(E1, Ri0*F1); \
        const float p10 = fmaxf(E0, Ri1*F0), p11 = fmaxf(E1, Ri1*F1); \
        unsigned int w0, w1; \
        asm("v_cvt_pk_bf16_f32 %0, %1, %2" : "=v"(w0) : "v"(p00), "v"(p01)); \
        asm("v_cvt_pk_bf16_f32 %0, %1, %2" : "=v"(w1) : "v"(p10), "v"(p11)); \
        const unsigned int k00 = (unsigned int)(((int)(sh0 << (31-2*p))) >> 31); \
        const unsigned int k01 = (unsigned int)(((int)(sh0 << (30-2*p))) >> 31); \
        const unsigned int k10 = (unsigned int)(((int)(sh1 << (31-2*p))) >> 31); \
        const unsigned int k11 = (unsigned int)(((int)(sh1 << (30-2*p))) >> 31); \
        aw0[p] = w0 & ((k00 & 0xFFFFu) | (k01 << 16)); \
        aw1[p] = w1 & ((k10 & 0xFFFFu) | (k11 << 16)); \
      } \
      const short8 af0 = *(const short8*)aw0; \
      const short8 af1 = *(const short8*)aw1; \
      _Pragma("unroll") \
      for (int c=0;c<8;++c){ \
        acc0[c] = __builtin_amdgcn_mfma_f32_16x16x32_bf16(af0, Bc_[(t<<3)+c], acc0[c], 0, 0, 0); \
        acc1[c] = __builtin_amdgcn_mfma_f32_16x16x32_bf16(af1, Bc_[(t<<3)+c], acc1[c], 0, 0, 0); \
      } \
      lf0 = __builtin_amdgcn_mfma_f32_16x16x32_bf16(af0, ones8, lf0, 0, 0, 0); \
      lf1 = __builtin_amdgcn_mfma_f32_16x16x32_bf16(af1, ones8, lf1, 0, 0, 0); \
    } \
  } while(0)

  __syncthreads();                 // sEj staged (drains prologue loads; one-time cost)

  BALLOTS(vv, 0, 0);               // superchunk 0 halves -> buf0
  BALLOTS(vp, 0, 1);

  #pragma unroll 1
  for (int sc = 0; sc < 3; ++sc){
    { short8 Bc[16]; BCLOAD(Bc, (sc<<2)|0); LOADVV(vv, sc+1, 0); COMPUTE_CH(sc, 0, Bc); }
    { short8 Bc[16]; BCLOAD(Bc, (sc<<2)|1); COMPUTE_CH(sc, 1, Bc); }   // drains vv half0
    BALLOTS(vv, sc+1, 0);
    { short8 Bc[16]; BCLOAD(Bc, (sc<<2)|2); LOADVV(vv, sc+1, 1); COMPUTE_CH(sc, 2, Bc); }
    { short8 Bc[16]; BCLOAD(Bc, (sc<<2)|3); COMPUTE_CH(sc, 3, Bc); }   // drains vv half1
    BALLOTS(vv, sc+1, 1);
  }
  { short8 Bc[16]; BCLOAD(Bc, 12); COMPUTE_CH(3, 0, Bc); }
  { short8 Bc[16]; BCLOAD(Bc, 13); COMPUTE_CH(3, 1, Bc); }
  { short8 Bc[16]; BCLOAD(Bc, 14); COMPUTE_CH(3, 2, Bc); }
  { short8 Bc[16]; BCLOAD(Bc, 15); COMPUTE_CH(3, 3, Bc); }

#undef COMPUTE_CH
#undef BCLOAD
#undef BALLOTS
#undef LOADVV

  // cross-wave combine, two passes (rowgroup 0 then 1); stride 132 for float4-aligned reads
  #pragma unroll 1
  for (int g = 0; g < 2; ++g){
    __syncthreads();
    #pragma unroll
    for (int c=0;c<8;++c){
      #pragma unroll
      for (int r=0;r<4;++r){
        const float v = g ? acc1[c][r] : acc0[c][r];
        smemc[(wave*16 + quad*4 + r)*132 + c*16 + m] = v;
      }
    }
    if (m == 0){
      #pragma unroll
      for (int r=0;r<4;++r) smemc[8448 + wave*16 + quad*4 + r] = g ? lf1[r] : lf0[r];
    }
    __syncthreads();

    const int rr = tid >> 5;
    const int c4 = (tid & 31) << 2;
    #pragma unroll
    for (int hh = 0; hh < 2; ++hh){
      const int row = rr + (hh<<3);
      const float l = smemc[8448+row] + smemc[8448+16+row]
                    + smemc[8448+32+row] + smemc[8448+48+row];
      const float rl = __builtin_amdgcn_rcpf(l);       // ~1 ulp, replaces 8 f32 divides
      float4 o4;
      #pragma unroll
      for (int k=0;k<4;++k){
        const int col = c4 + k;
        const float s = smemc[row*132+col] + smemc[(16+row)*132+col]
                      + smemc[(32+row)*132+col] + smemc[(48+row)*132+col];
        float v = s * rl;
        v = v > 0.f ? v : expm1f(v);                   // ELU (alpha=1)
        ((float*)&o4)[k] = v;
      }
      *(float4*)&out[((size_t)(b*GN + i0 + (g<<4) + row))*GF + c4] = o4;
    }
  }
}

extern "C" void kernel_launch(void* const* d_in, const int* in_sizes, int n_in,
                              void* d_out, int out_size, void* d_ws, size_t ws_size,
                              hipStream_t stream)
{
  (void)in_sizes; (void)n_in; (void)out_size; (void)ws_size;
  const float* h   = (const float*)d_in[0];
  const int*   adj = (const int*)d_in[1];
  const float* W   = (const float*)d_in[2];
  const float* a   = (const float*)d_in[3];
  float* out = (float*)d_out;

  char* ws = (char*)d_ws;
  unsigned short* whB   = (unsigned short*)ws;                    // 4 MB fragment-major (J4-order)
  float*          si    = (float*)(ws + (size_t)4*1024*1024);     // 64 KB
  unsigned short* EFh   = (unsigned short*)(ws + (size_t)4*1024*1024 + 64*1024);   // 64 KB

  gat_prep<<<GB*GN/16, 256, 0, stream>>>(h, W, a, whB, si, EFh);
  gat_main<<<GB*GN/32, 256, 0, stream>>>(adj, whB, si, EFh, out);
}